// Round 3
// baseline (421.169 us; speedup 1.0000x reference)
//
#include <hip/hip_runtime.h>

// Fixed problem shape
constexpr int S_DIM = 8;
constexpr int B_DIM = 16;
constexpr int H = 512;
constexpr int W = 512;
constexpr int PLANE = H * W;
constexpr long long NTOT = (long long)S_DIM * B_DIM * H * W;   // 33554432
constexpr int ROWS = 4;                    // output rows per wave-task
constexpr int RBLKS = H / ROWS;            // 128 row-blocks per plane
constexpr int NPLANES = S_DIM * B_DIM;     // 128
constexpr int NTASKS = NPLANES * RBLKS;    // 16384
constexpr int NBLOCKS = 2048;
constexpr int NWAVES = NBLOCKS * 4;        // 8192 waves
constexpr int TASKS_PER_WAVE = NTASKS / NWAVES;  // 2
constexpr float BIG = 1e30f;

__device__ __forceinline__ float weight_of(float t) {
    // {1,2,5,10,30} at thresholds {2,5,10,30}
    float w = 1.0f;
    if (t >= 2.0f)  w = 2.0f;
    if (t >= 5.0f)  w = 5.0f;
    if (t >= 10.0f) w = 10.0f;
    if (t >= 30.0f) w = 30.0f;
    return w;
}

__device__ __forceinline__ float min3f(float a, float b, float c) {
    return fminf(fminf(a, b), c);   // fuses to v_min3_f32 (abs mods fold in)
}

struct PRow {
    float p[8];   // this lane's 8 columns of one pred row
    float l, r;   // left neighbor (lane-1 col7), right neighbor (lane+1 col0)
};

__device__ __forceinline__ void load_prow(const float* __restrict__ q, int lane, PRow& w) {
    const float4 a = *reinterpret_cast<const float4*>(q);
    const float4 b = *reinterpret_cast<const float4*>(q + 4);
    w.p[0] = a.x; w.p[1] = a.y; w.p[2] = a.z; w.p[3] = a.w;
    w.p[4] = b.x; w.p[5] = b.y; w.p[6] = b.z; w.p[7] = b.w;
    w.l = __shfl_up(b.w, 1);     // lane-1's col 7
    w.r = __shfl_down(a.x, 1);   // lane+1's col 0
    if (lane == 0)  w.l = BIG;   // true image boundary (col -1)
    if (lane == 63) w.r = BIG;   // true image boundary (col 512)
}

__device__ __forceinline__ void accum_row(const PRow& pw, const float (&t)[8], float (&mn)[8]) {
    mn[0] = fminf(mn[0], min3f(fabsf(t[0] - pw.l),
                               fabsf(t[0] - pw.p[0]),
                               fabsf(t[0] - pw.p[1])));
    #pragma unroll
    for (int c = 1; c < 7; ++c)
        mn[c] = fminf(mn[c], min3f(fabsf(t[c] - pw.p[c - 1]),
                                   fabsf(t[c] - pw.p[c]),
                                   fabsf(t[c] - pw.p[c + 1])));
    mn[7] = fminf(mn[7], min3f(fabsf(t[7] - pw.p[6]),
                               fabsf(t[7] - pw.p[7]),
                               fabsf(t[7] - pw.r)));
}

__global__ __launch_bounds__(256)
void wmae_main(const float* __restrict__ pred,
               const float* __restrict__ targ,
               const int*   __restrict__ mask,
               double*      __restrict__ ws_sum,   // ws_sum[0]=sum, ((unsigned*)ws_sum)[2]=counter
               float*       __restrict__ out) {
    const int tid  = threadIdx.x;
    const int lane = tid & 63;
    const int wv   = blockIdx.x * 4 + (tid >> 6);
    const int col0 = lane * 8;

    float acc = 0.0f;

    #pragma unroll
    for (int ti = 0; ti < TASKS_PER_WAVE; ++ti) {
        const int tt = wv + ti * NWAVES;
        const int pl = tt >> 7;                      // target plane (b*S + s)
        const int r0 = (tt & (RBLKS - 1)) * ROWS;
        const int b  = pl >> 3;
        const int s  = pl & 7;

        const float* __restrict__ P = pred + (size_t)(s * B_DIM + b) * PLANE + col0;
        const float* __restrict__ T = targ + (size_t)pl * PLANE + col0;
        const int*   __restrict__ M = mask + (size_t)pl * PLANE + col0;

        PRow w0, w1, w2;
        load_prow(P + (size_t)(r0 > 0 ? r0 - 1 : 0) * W, lane, w0);  // row r0-1 (clamped)
        load_prow(P + (size_t)r0 * W, lane, w1);                     // row r0

        #pragma unroll
        for (int rr = 0; rr < ROWS; ++rr) {
            const int r = r0 + rr;
            // rotating 3-slot window (all selections compile-time after unroll)
            PRow& wm = (rr % 3 == 0) ? w0 : (rr % 3 == 1) ? w1 : w2;  // row r-1
            PRow& wc = (rr % 3 == 0) ? w1 : (rr % 3 == 1) ? w2 : w0;  // row r
            PRow& wp = (rr % 3 == 0) ? w2 : (rr % 3 == 1) ? w0 : w1;  // row r+1

            load_prow(P + (size_t)(r + 1 < H ? r + 1 : H - 1) * W, lane, wp);

            const float* Tr = T + (size_t)r * W;
            const int*   Mr = M + (size_t)r * W;
            const float4 ta = *reinterpret_cast<const float4*>(Tr);
            const float4 tb = *reinterpret_cast<const float4*>(Tr + 4);
            const int4   ma = *reinterpret_cast<const int4*>(Mr);
            const int4   mb = *reinterpret_cast<const int4*>(Mr + 4);

            const float t[8] = {ta.x, ta.y, ta.z, ta.w, tb.x, tb.y, tb.z, tb.w};
            float wgt[8];
            wgt[0] = weight_of(t[0]) * (float)ma.x;
            wgt[1] = weight_of(t[1]) * (float)ma.y;
            wgt[2] = weight_of(t[2]) * (float)ma.z;
            wgt[3] = weight_of(t[3]) * (float)ma.w;
            wgt[4] = weight_of(t[4]) * (float)mb.x;
            wgt[5] = weight_of(t[5]) * (float)mb.y;
            wgt[6] = weight_of(t[6]) * (float)mb.z;
            wgt[7] = weight_of(t[7]) * (float)mb.w;

            float mn[8];
            #pragma unroll
            for (int c = 0; c < 8; ++c) mn[c] = BIG;

            if (rr > 0 || r0 > 0) accum_row(wm, t, mn);   // pred row r-1 valid
            accum_row(wc, t, mn);                          // row r always valid
            if (r + 1 < H)        accum_row(wp, t, mn);   // pred row r+1 valid

            float rs = 0.0f;
            #pragma unroll
            for (int c = 0; c < 8; ++c) rs += wgt[c] * mn[c];
            acc += rs;
        }
    }

    // wave64 reduce
    #pragma unroll
    for (int off = 32; off > 0; off >>= 1)
        acc += __shfl_down(acc, off);

    __shared__ float wsum[4];
    const int wid = tid >> 6;
    if (lane == 0) wsum[wid] = acc;
    __syncthreads();

    if (tid == 0) {
        const float bsum = wsum[0] + wsum[1] + wsum[2] + wsum[3];
        atomicAdd(ws_sum, (double)bsum);
        __threadfence();
        unsigned* ctr = reinterpret_cast<unsigned*>(ws_sum) + 2;
        const unsigned prev = atomicAdd(ctr, 1u);
        if (prev == (unsigned)gridDim.x - 1u) {
            // last block: all sum-adds are visible at device scope; read via atomic
            const double total = atomicAdd(ws_sum, 0.0);
            out[0] = (float)(total / (double)NTOT);
        }
    }
}

extern "C" void kernel_launch(void* const* d_in, const int* in_sizes, int n_in,
                              void* d_out, int out_size, void* d_ws, size_t ws_size,
                              hipStream_t stream) {
    const float* predicted = (const float*)d_in[0];  // (S,B,H,W)
    const float* target    = (const float*)d_in[1];  // (B,S,H,W)
    const int*   mask      = (const int*)d_in[2];    // (B,S,H,W)
    float*  out = (float*)d_out;
    double* wsd = (double*)d_ws;

    hipMemsetAsync(wsd, 0, 16, stream);  // sum (8B) + counter (4B), ws re-poisoned each replay
    wmae_main<<<NBLOCKS, 256, 0, stream>>>(predicted, target, mask, wsd, out);
}

// Round 4
// 364.233 us; speedup vs baseline: 1.1563x; 1.1563x over previous
//
#include <hip/hip_runtime.h>

// Fixed problem shape
constexpr int S_DIM = 8;
constexpr int B_DIM = 16;
constexpr int H = 512;
constexpr int W = 512;
constexpr int PLANE = H * W;
constexpr long long NTOT = (long long)S_DIM * B_DIM * H * W;   // 33554432
constexpr int NBLOCKS = 2048;
constexpr int TPB = 256;
constexpr int NTHREADS = NBLOCKS * TPB;        // 524288
constexpr int CHUNK = 16;                      // floats per thread-iteration
constexpr int NCHUNK = (int)(NTOT / CHUNK);    // 2097152  (exactly 4 iters/thread)
constexpr int CPR = W / CHUNK;                 // 32 chunks per row
constexpr int CPP = PLANE / CHUNK;             // 16384 chunks per plane (2^14)
constexpr float BIG = 1e30f;
constexpr int NSLOT = 64;

__device__ __forceinline__ float weight_of(float t) {
    // {1,2,5,10,30} at thresholds {2,5,10,30}
    float w = 1.0f;
    if (t >= 2.0f)  w = 2.0f;
    if (t >= 5.0f)  w = 5.0f;
    if (t >= 10.0f) w = 10.0f;
    if (t >= 30.0f) w = 30.0f;
    return w;
}

__device__ __forceinline__ float min3f(float a, float b, float c) {
    return fminf(fminf(a, b), c);   // fuses to v_min3_f32, abs mods fold in
}

__global__ __launch_bounds__(TPB)
void wmae_main(const float* __restrict__ pred,
               const float* __restrict__ targ,
               const int*   __restrict__ mask,
               double*      __restrict__ slots) {
    const int tid = threadIdx.x;
    float acc = 0.0f;

    #pragma unroll 1   // keep one iteration's registers live, not four
    for (int c = blockIdx.x * TPB + tid; c < NCHUNK; c += NTHREADS) {
        const int pl  = c >> 14;             // plane (b*S + s), CPP = 2^14
        const int rem = c & (CPP - 1);
        const int row = rem >> 5;            // CPR = 32
        const int cx  = rem & (CPR - 1);
        const int b   = pl >> 3;
        const int s   = pl & 7;

        const size_t tb = (size_t)pl * PLANE + (size_t)row * W + cx * CHUNK;
        const float* __restrict__ T  = targ + tb;
        const int*   __restrict__ M  = mask + tb;
        const float* __restrict__ Pc = pred + (size_t)(s * B_DIM + b) * PLANE
                                            + (size_t)row * W + cx * CHUNK;
        const float* __restrict__ Pm = Pc + ((row > 0)     ? -W : 0);  // clamped
        const float* __restrict__ Pp = Pc + ((row < H - 1) ?  W : 0);  // clamped
        const int lo = (cx > 0)       ? -1    : 0;          // clamped edge offsets
        const int ro = (cx < CPR - 1) ? CHUNK : CHUNK - 1;

        // ---- all 18 loads issued up-front, fully independent ----
        const float4 t0 = *reinterpret_cast<const float4*>(T);
        const float4 t1 = *reinterpret_cast<const float4*>(T + 4);
        const float4 t2 = *reinterpret_cast<const float4*>(T + 8);
        const float4 t3 = *reinterpret_cast<const float4*>(T + 12);
        const int4   q0 = *reinterpret_cast<const int4*>(M);
        const int4   q1 = *reinterpret_cast<const int4*>(M + 4);
        const int4   q2 = *reinterpret_cast<const int4*>(M + 8);
        const int4   q3 = *reinterpret_cast<const int4*>(M + 12);
        const float4 pc0 = *reinterpret_cast<const float4*>(Pc);
        const float4 pc1 = *reinterpret_cast<const float4*>(Pc + 4);
        const float4 pc2 = *reinterpret_cast<const float4*>(Pc + 8);
        const float4 pc3 = *reinterpret_cast<const float4*>(Pc + 12);
        const float  pcl = Pc[lo], pcr = Pc[ro];
        const float4 pa0 = *reinterpret_cast<const float4*>(Pm);
        const float4 pa1 = *reinterpret_cast<const float4*>(Pm + 4);
        const float4 pa2 = *reinterpret_cast<const float4*>(Pm + 8);
        const float4 pa3 = *reinterpret_cast<const float4*>(Pm + 12);
        const float  pal = Pm[lo], par = Pm[ro];
        const float4 pb0 = *reinterpret_cast<const float4*>(Pp);
        const float4 pb1 = *reinterpret_cast<const float4*>(Pp + 4);
        const float4 pb2 = *reinterpret_cast<const float4*>(Pp + 8);
        const float4 pb3 = *reinterpret_cast<const float4*>(Pp + 12);
        const float  pbl = Pp[lo], pbr = Pp[ro];

        // ---- compute ----
        const float tt[16] = {t0.x,t0.y,t0.z,t0.w, t1.x,t1.y,t1.z,t1.w,
                              t2.x,t2.y,t2.z,t2.w, t3.x,t3.y,t3.z,t3.w};
        const int   mm[16] = {q0.x,q0.y,q0.z,q0.w, q1.x,q1.y,q1.z,q1.w,
                              q2.x,q2.y,q2.z,q2.w, q3.x,q3.y,q3.z,q3.w};
        float ww[16];
        #pragma unroll
        for (int i = 0; i < 16; ++i) ww[i] = weight_of(tt[i]) * (float)mm[i];

        const bool hasL = (cx > 0), hasR = (cx < CPR - 1);

        float ctr[18];
        ctr[0]  = hasL ? pcl : BIG;
        ctr[17] = hasR ? pcr : BIG;
        ctr[1]=pc0.x; ctr[2]=pc0.y; ctr[3]=pc0.z; ctr[4]=pc0.w;
        ctr[5]=pc1.x; ctr[6]=pc1.y; ctr[7]=pc1.z; ctr[8]=pc1.w;
        ctr[9]=pc2.x; ctr[10]=pc2.y; ctr[11]=pc2.z; ctr[12]=pc2.w;
        ctr[13]=pc3.x; ctr[14]=pc3.y; ctr[15]=pc3.z; ctr[16]=pc3.w;

        float mn[16];
        #pragma unroll
        for (int i = 0; i < 16; ++i)
            mn[i] = min3f(fabsf(tt[i] - ctr[i]),
                          fabsf(tt[i] - ctr[i + 1]),
                          fabsf(tt[i] - ctr[i + 2]));

        if (row > 0) {                       // pred row r-1 contributes
            float up[18];
            up[0]  = hasL ? pal : BIG;
            up[17] = hasR ? par : BIG;
            up[1]=pa0.x; up[2]=pa0.y; up[3]=pa0.z; up[4]=pa0.w;
            up[5]=pa1.x; up[6]=pa1.y; up[7]=pa1.z; up[8]=pa1.w;
            up[9]=pa2.x; up[10]=pa2.y; up[11]=pa2.z; up[12]=pa2.w;
            up[13]=pa3.x; up[14]=pa3.y; up[15]=pa3.z; up[16]=pa3.w;
            #pragma unroll
            for (int i = 0; i < 16; ++i)
                mn[i] = fminf(mn[i], min3f(fabsf(tt[i] - up[i]),
                                           fabsf(tt[i] - up[i + 1]),
                                           fabsf(tt[i] - up[i + 2])));
        }
        if (row < H - 1) {                   // pred row r+1 contributes
            float dn[18];
            dn[0]  = hasL ? pbl : BIG;
            dn[17] = hasR ? pbr : BIG;
            dn[1]=pb0.x; dn[2]=pb0.y; dn[3]=pb0.z; dn[4]=pb0.w;
            dn[5]=pb1.x; dn[6]=pb1.y; dn[7]=pb1.z; dn[8]=pb1.w;
            dn[9]=pb2.x; dn[10]=pb2.y; dn[11]=pb2.z; dn[12]=pb2.w;
            dn[13]=pb3.x; dn[14]=pb3.y; dn[15]=pb3.z; dn[16]=pb3.w;
            #pragma unroll
            for (int i = 0; i < 16; ++i)
                mn[i] = fminf(mn[i], min3f(fabsf(tt[i] - dn[i]),
                                           fabsf(tt[i] - dn[i + 1]),
                                           fabsf(tt[i] - dn[i + 2])));
        }

        float rs = 0.0f;
        #pragma unroll
        for (int i = 0; i < 16; ++i) rs += ww[i] * mn[i];
        acc += rs;
    }

    // wave64 reduce, then block reduce, then one atomic per block into 64 slots
    #pragma unroll
    for (int off = 32; off > 0; off >>= 1)
        acc += __shfl_down(acc, off);

    __shared__ float ws4[4];
    const int wid  = tid >> 6;
    const int lane = tid & 63;
    if (lane == 0) ws4[wid] = acc;
    __syncthreads();
    if (tid == 0) {
        const float bsum = ws4[0] + ws4[1] + ws4[2] + ws4[3];
        atomicAdd(&slots[blockIdx.x & (NSLOT - 1)], (double)bsum);
    }
}

__global__ void wmae_fin(const double* __restrict__ slots,
                         float* __restrict__ out) {
    double v = slots[threadIdx.x];   // 64 threads = 1 wave
    #pragma unroll
    for (int off = 32; off > 0; off >>= 1)
        v += __shfl_down(v, off);
    if (threadIdx.x == 0) out[0] = (float)(v / (double)NTOT);
}

extern "C" void kernel_launch(void* const* d_in, const int* in_sizes, int n_in,
                              void* d_out, int out_size, void* d_ws, size_t ws_size,
                              hipStream_t stream) {
    const float* predicted = (const float*)d_in[0];  // (S,B,H,W)
    const float* target    = (const float*)d_in[1];  // (B,S,H,W)
    const int*   mask      = (const int*)d_in[2];    // (B,S,H,W)
    float*  out = (float*)d_out;
    double* wsd = (double*)d_ws;

    hipMemsetAsync(wsd, 0, NSLOT * sizeof(double), stream);  // ws re-poisoned each replay
    wmae_main<<<NBLOCKS, TPB, 0, stream>>>(predicted, target, mask, wsd);
    wmae_fin<<<1, 64, 0, stream>>>(wsd, out);
}